// Round 18
// baseline (146.931 us; speedup 1.0000x reference)
//
#include <hip/hip_runtime.h>
#include <cstdint>

typedef _Float16 f16;
typedef __attribute__((ext_vector_type(2))) _Float16 f16x2;
typedef __attribute__((ext_vector_type(4))) _Float16 f16x4;
typedef __attribute__((ext_vector_type(8))) _Float16 f16x8;
typedef __attribute__((ext_vector_type(4))) float f32x4;

#define NB 2
#define NH 46
#define NW 96
#define NHW 4416
#define ND 256
#define NTILES 276   // NHW / 16
#define SSTR 4424    // fused-path LDS S stride
#define L2E 1.44269504f

// ---- workspace byte offsets ----
#define OFF_WFQ 0          // (Wf@Wq)/16  f16 [256][256]
#define OFF_WFK 131072     // Wf@Wk       f16 [256][256]
#define OFF_PQ  262144     // (Wpos@Wq)/16 f32 [2][256]
#define OFF_PK  264192     // Wpos@Wk      f32 [2][256]
#define OFF_BQ  266240     // (bf@Wq)/16   f32 [256]
#define OFF_BK  267264     // bf@Wk        f32 [256]
#define OFF_GS  268288     // (Wpos@Wposᵀ)/16 f32 [2][2]
#define OFF_Q   268544     // q/16 f16 [8832][256]
#define OFF_K   4790528    // k    f16 [8832][256]
// ---- unfused-path extras ----
#define OFF_RM  9312512    // per-slice row max f16 [2][8][4416] (141,312 B exact)
#define OFF_S   9453824    // scores f16 [2][4416][SCOL]
#define SCOL    4432       // 4416 + 16 pad
#define WS_NEED 87740672UL // OFF_S + 2*4416*4432*2

// ============ K0: tiny weight-product precompute ============
__global__ __launch_bounds__(256) void prep_kernel(
    const float* __restrict__ Wf, const float* __restrict__ bf,
    const float* __restrict__ Wpos, const float* __restrict__ Wq,
    const float* __restrict__ Wk, char* __restrict__ ws) {
  f16* WFQ = (f16*)(ws + OFF_WFQ);
  f16* WFK = (f16*)(ws + OFF_WFK);
  float* PQ = (float*)(ws + OFF_PQ);
  float* PK = (float*)(ws + OFF_PK);
  float* BQ = (float*)(ws + OFF_BQ);
  float* BK = (float*)(ws + OFF_BK);
  float* GS = (float*)(ws + OFF_GS);
  int bid = blockIdx.x, d = threadIdx.x;
  if (bid < 256) {
    int c = bid;
    float aq = 0.f, ak = 0.f;
#pragma unroll 8
    for (int t = 0; t < 256; ++t) {
      float wf = Wf[c * 256 + t];
      aq += wf * Wq[t * 256 + d];
      ak += wf * Wk[t * 256 + d];
    }
    WFQ[c * 256 + d] = (f16)(aq * 0.0625f);
    WFK[c * 256 + d] = (f16)ak;
  } else if (bid == 256) {
    float pq0 = 0, pq1 = 0, pk0 = 0, pk1 = 0, bq = 0, bk = 0;
#pragma unroll 4
    for (int c = 0; c < 256; ++c) {
      float wq = Wq[c * 256 + d], wk = Wk[c * 256 + d];
      pq0 += Wpos[c] * wq;       pq1 += Wpos[256 + c] * wq;
      pk0 += Wpos[c] * wk;       pk1 += Wpos[256 + c] * wk;
      bq  += bf[c] * wq;         bk  += bf[c] * wk;
    }
    PQ[d] = pq0 * 0.0625f; PQ[256 + d] = pq1 * 0.0625f;
    PK[d] = pk0;           PK[256 + d] = pk1;
    BQ[d] = bq * 0.0625f;  BK[d] = bk;
  } else if (d < 4) {
    int a = d >> 1, b2 = d & 1;
    float g = 0;
    for (int t = 0; t < 256; ++t) g += Wpos[a * 256 + t] * Wpos[b2 * 256 + t];
    GS[d] = g * 0.0625f;
  }
}

// ============ K1: q_s/k = fmapᵀ @ Wfx + rank-2 pos + bias (256-col tile) ============
// grid (138, 1, 2): x = 64-row tile, z = 0:q 1:k. 256 thr (4 waves). [R15 proven]
__global__ __launch_bounds__(256, 2) void qk_gemm(
    const float* __restrict__ fmap1, const float* __restrict__ fmap2,
    const float* __restrict__ coords1, char* __restrict__ ws) {
  __shared__ f16 As[64 * 40];
  __shared__ f16 Bs[256 * 40];
  __shared__ float py[64], px[64];
  const int z = blockIdx.z;
  const float* fmap = z ? fmap2 : fmap1;
  const f16* Wt = (const f16*)(ws + (z ? OFF_WFK : OFF_WFQ));
  const float* P = (const float*)(ws + (z ? OFF_PK : OFF_PQ));
  const float* bias = (const float*)(ws + (z ? OFF_BK : OFF_BQ));
  f16* outb = (f16*)(ws + (z ? OFF_K : OFF_Q));
  const int t = threadIdx.x;
  const int g0 = blockIdx.x * 64;
  const int b = g0 / NHW;
  const int hwb = g0 - b * NHW;
  if (t < 64) {
    int hw = hwb + t;
    if (z == 0) {
      py[t] = coords1[(b * 2 + 1) * NHW + hw];
      px[t] = coords1[(b * 2 + 0) * NHW + hw];
    } else {
      int y = hw / NW;
      py[t] = (float)y;
      px[t] = (float)(hw - y * NW);
    }
  }
  const int lane = t & 63, wave = t >> 6;
  const int wr = (wave >> 1) * 32, wc0 = (wave & 1) * 128;
  const int hwl = t & 63, cl0 = t >> 6;
  const int dd = t & 127, ch = t >> 7;
  f32x4 acc[2][8] = {};
  for (int kt = 0; kt < 8; ++kt) {
    int kk = kt * 32;
    __syncthreads();
#pragma unroll
    for (int i = 0; i < 8; ++i) {
      int c = cl0 + i * 4;
      As[hwl * 40 + c] = (f16)fmap[(size_t)(b * ND + kk + c) * NHW + hwb + hwl];
    }
#pragma unroll
    for (int i = 0; i < 16; ++i) {
      int c = ch * 16 + i;
      Bs[dd * 40 + c] = Wt[(kk + c) * ND + dd];
      Bs[(dd + 128) * 40 + c] = Wt[(kk + c) * ND + dd + 128];
    }
    __syncthreads();
    int row = lane & 15, kq = (lane >> 4) * 8;
    f16x8 a0 = *(const f16x8*)&As[(wr + row) * 40 + kq];
    f16x8 a1 = *(const f16x8*)&As[(wr + 16 + row) * 40 + kq];
#pragma unroll
    for (int s = 0; s < 8; ++s) {
      f16x8 bs = *(const f16x8*)&Bs[(wc0 + 16 * s + row) * 40 + kq];
      acc[0][s] = __builtin_amdgcn_mfma_f32_16x16x32_f16(a0, bs, acc[0][s], 0, 0, 0);
      acc[1][s] = __builtin_amdgcn_mfma_f32_16x16x32_f16(a1, bs, acc[1][s], 0, 0, 0);
    }
  }
#pragma unroll
  for (int fi = 0; fi < 2; ++fi)
#pragma unroll
    for (int s = 0; s < 8; ++s)
#pragma unroll
      for (int r = 0; r < 4; ++r) {
        int rowl = wr + fi * 16 + (lane >> 4) * 4 + r;
        int d = wc0 + s * 16 + (lane & 15);
        float v = acc[fi][s][r] + bias[d] + py[rowl] * P[d] + px[rowl] * P[ND + d];
        outb[(size_t)(g0 + rowl) * ND + d] = (f16)v;
      }
}

// ============ Ka: scores GEMM v11 — R10 block, half-N slices, grid 736 ============
// grid 736 = 46 Mtiles(96 rows) x 16 (batch x 8 N-slices). blk&7 = ns -> each
// XCD streams one ~560-col K-slice of both batches (566 KB, L2-resident).
// 512 blocks co-resident (2/CU) + 224 backfill -> makespan ~1.44 x T_half.
// Slices: 4x34 + 4x35 16-col tiles (starts 0,34,68,102,136,171,206,241).
// Per-slice rowmax stored f16 in OFF_RM [2][8][4416].
__global__ __launch_bounds__(384, 2) void score_gemm(
    const float* __restrict__ coords1, char* __restrict__ ws) {
  __shared__ f16 kls[2][32][264];      // K-tile dbuf, row-pad 264
  __shared__ f16 stw[6][16][36];       // per-wave repack [qrow][32col + pad]
  __shared__ float u0s[96], u1s[96];
  const int tid = threadIdx.x;
  const int blk = blockIdx.x;
  const int comb = blk & 15;
  const int b = comb >> 3, ns = comb & 7;
  const int hw0 = (blk >> 4) * 96;
  const int sstart[9] = {0, 34, 68, 102, 136, 171, 206, 241, 276};
  const int j00 = sstart[ns] * 16;
  const bool hastail = (sstart[ns + 1] - sstart[ns]) == 35;
  const int itmax = hastail ? 17 : 16;   // iters 0..itmax; it<17 are full 32-col
  const float* GS = (const float*)(ws + OFF_GS);
  if (tid < 96) {
    int hw = hw0 + tid;
    float cy = coords1[(b * 2 + 1) * NHW + hw];
    float cx = coords1[(b * 2 + 0) * NHW + hw];
    u0s[tid] = cy * GS[0] + cx * GS[2];
    u1s[tid] = cy * GS[1] + cx * GS[3];
  }
  const f16* __restrict__ qb = (const f16*)(ws + OFF_Q);
  const f16* __restrict__ kb = (const f16*)(ws + OFF_K);
  f16* __restrict__ gSb = (f16*)(ws + OFF_S) + ((size_t)b * NHW + hw0) * SCOL;
  f16* __restrict__ rm16 = (f16*)(ws + OFF_RM);
  const int lane = tid & 63, wave = tid >> 6;   // 6 waves
  const int q = lane & 15, h = lane >> 4;
  // wave's 16 Q-rows, full K=256: 32 VGPR
  f16x8 qfrag[8];
#pragma unroll
  for (int ks = 0; ks < 8; ++ks)
    qfrag[ks] = *(const f16x8*)&qb[(size_t)(b * NHW + hw0 + wave * 16 + q) * ND + ks * 32 + h * 8];
  // stage iter-0 tile into kls[0]
  for (int c = tid; c < 32 * 32; c += 384) {
    int r = c >> 5, cc = c & 31;
    *(f16x8*)&kls[0][r][cc * 8] =
        *(const f16x8*)&kb[(size_t)(b * NHW + j00 + r) * ND + cc * 8];
  }
  __syncthreads();
  const float u0m = u0s[wave * 16 + q], u1m = u1s[wave * 16 + q];
  float pmax = -3e38f;
  const int srow = lane >> 2, scg = lane & 3;   // store-phase mapping

  for (int it = 0; it <= itmax; ++it) {
    const int buf = it & 1;
    const int jp = j00 + it * 32;
    const bool full = (it < 17);
    // stage next tile into buf^1 (no one reads buf^1 this iter)
    if (it < itmax) {
      const int nW = (it + 1 < 17) ? 32 : 16;
      const int jn = j00 + (it + 1) * 32;
      for (int c = tid; c < nW * 32; c += 384) {
        int r = c >> 5, cc = c & 31;
        *(f16x8*)&kls[buf ^ 1][r][cc * 8] =
            *(const f16x8*)&kb[(size_t)(b * NHW + jn + r) * ND + cc * 8];
      }
    }
    // compute from kls[buf]
    f32x4 acc0 = {}, acc1 = {};
#pragma unroll
    for (int ks = 0; ks < 8; ++ks) {
      f16x8 kf = *(const f16x8*)&kls[buf][q][ks * 32 + h * 8];
      acc0 = __builtin_amdgcn_mfma_f32_16x16x32_f16(kf, qfrag[ks], acc0, 0, 0, 0);
    }
    if (full) {
#pragma unroll
      for (int ks = 0; ks < 8; ++ks) {
        f16x8 kf = *(const f16x8*)&kls[buf][16 + q][ks * 32 + h * 8];
        acc1 = __builtin_amdgcn_mfma_f32_16x16x32_f16(kf, qfrag[ks], acc1, 0, 0, 0);
      }
    }
    // epilogue: bias + running max + pack to stw
    {
      f16x4 v0, v1;
#pragma unroll
      for (int r = 0; r < 4; ++r) {
        int j = jp + h * 4 + r;
        int yj = j / NW;
        float s = acc0[r] + u0m * (float)yj + u1m * (float)(j - yj * NW);
        pmax = fmaxf(pmax, s);
        v0[r] = (f16)s;
      }
      *(f16x4*)&stw[wave][q][h * 4] = v0;
      if (full) {
#pragma unroll
        for (int r = 0; r < 4; ++r) {
          int j = jp + 16 + h * 4 + r;
          int yj = j / NW;
          float s = acc1[r] + u0m * (float)yj + u1m * (float)(j - yj * NW);
          pmax = fmaxf(pmax, s);
          v1[r] = (f16)s;
        }
        *(f16x4*)&stw[wave][q][16 + h * 4] = v1;
      }
    }
    // store: 64B (or 32B tail) contiguous per row
    if (full) {
      f16x8 row8 = *(const f16x8*)&stw[wave][srow][scg * 8];
      *(f16x8*)&gSb[(size_t)(wave * 16 + srow) * SCOL + jp + scg * 8] = row8;
    } else {
      f16x4 row4 = *(const f16x4*)&stw[wave][srow][scg * 4];
      *(f16x4*)&gSb[(size_t)(wave * 16 + srow) * SCOL + jp + scg * 4] = row4;
    }
    __syncthreads();   // stage(it+1) done AND compute(buf) done before reuse
  }
  // per-slice rowmax (f16) -> rm16[b][ns][row]
  pmax = fmaxf(pmax, __shfl_xor(pmax, 16));
  pmax = fmaxf(pmax, __shfl_xor(pmax, 32));
  if (lane < 16)
    rm16[((size_t)b * 8 + ns) * NHW + hw0 + wave * 16 + q] = (f16)pmax;
}

// ============ Kb: lookup v2 — one wave per row, barrier-free, windowed lvl0 ============
// [R14 proven] 552 blocks x 512 thr (8 waves x 2 rows each). Max of 8 f16 slice maxes.
__global__ __launch_bounds__(512) void lookup_kernel(
    const float* __restrict__ clup, const char* __restrict__ ws,
    float* __restrict__ out) {
  __shared__ f16 lv1W[8][1104];
  __shared__ f16 lv2W[8][264];
  __shared__ f16 lv3W[8][60];
  __shared__ f16 winW[8][10][24];
  const int tid = threadIdx.x;
  const int blk0 = blockIdx.x;
  const int xcd = blk0 & 7;
  const int b = xcd >> 2;
  const int hw0 = ((blk0 >> 3) * 4 + (xcd & 3)) * 16;
  const f16* gS = (const f16*)(ws + OFF_S);
  const f16* rm16 = (const f16*)(ws + OFF_RM);
  const int lane = tid & 63, wave = tid >> 6;
  f16* lv1 = lv1W[wave];
  f16* lv2 = lv2W[wave];
  f16* lv3 = lv3W[wave];

  for (int rr2 = 0; rr2 < 2; ++rr2) {
    const int r = wave * 2 + rr2;
    const int hw = hw0 + r;
    const size_t grow = (size_t)b * NHW + hw;
    const f16* sp = gS + grow * SCOL;
    const float clx = clup[(b * 2 + 0) * NHW + hw];
    const float cly = clup[(b * 2 + 1) * NHW + hw];
    const f16* rp = rm16 + (size_t)b * 8 * NHW + hw;
    float m = (float)rp[0];
#pragma unroll
    for (int k = 1; k < 8; ++k) m = fmaxf(m, (float)rp[(size_t)k * NHW]);
    const int wy0 = (int)floorf(cly) - 4;
    const int wx0 = (int)floorf(clx) - 4;
    const int xb = (wx0 >> 3) << 3;       // 8-aligned floor (works for negatives)
    // --- stage 10x24 raw-S window (lanes 0..29: row=l/3, chunk=l%3) ---
    if (lane < 30) {
      int r10 = lane / 3, chk = lane - r10 * 3;
      int yy = wy0 + r10;
      int xc = xb + chk * 8;
      if (yy >= 0 && yy < NH) {
        if (xc >= 0 && xc + 8 <= NW) {
          *(f16x8*)&winW[wave][r10][chk * 8] = *(const f16x8*)&sp[yy * NW + xc];
        } else {
#pragma unroll
          for (int e = 0; e < 8; ++e) {
            int x = xc + e;
            winW[wave][r10][chk * 8 + e] =
                (x >= 0 && x < NW) ? sp[yy * NW + x] : (f16)0.f;
          }
        }
      }
    }
    // --- lvl1: exp-pool 2x2, 4 cells per f16x8-pair (u = y1*12 + g) ---
    float psum = 0.f;
    for (int u = lane; u < 276; u += 64) {
      int y1 = u / 12, g = u - y1 * 12;
      f16x8 A = *(const f16x8*)&sp[(2 * y1) * NW + g * 8];
      f16x8 B = *(const f16x8*)&sp[(2 * y1 + 1) * NW + g * 8];
      f16x4 v;
#pragma unroll
      for (int e = 0; e < 4; ++e) {
        float e00 = __builtin_amdgcn_exp2f(((float)A[2 * e] - m) * L2E);
        float e01 = __builtin_amdgcn_exp2f(((float)A[2 * e + 1] - m) * L2E);
        float e10 = __builtin_amdgcn_exp2f(((float)B[2 * e] - m) * L2E);
        float e11 = __builtin_amdgcn_exp2f(((float)B[2 * e + 1] - m) * L2E);
        float s4 = (e00 + e01) + (e10 + e11);
        v[e] = (f16)s4;
        psum += s4;
      }
      *(f16x4*)&lv1[y1 * 48 + g * 4] = v;
    }
#pragma unroll
    for (int off = 1; off < 64; off <<= 1) psum += __shfl_xor(psum, off);
    const float rinv = 1.f / psum;
    __threadfence_block();
    // --- lvl2 ---
    for (int c2 = lane; c2 < 264; c2 += 64) {
      int yy = c2 / 24, xx = c2 - yy * 24;
      f16x2 a = *(const f16x2*)&lv1[(2 * yy) * 48 + 2 * xx];
      f16x2 bb = *(const f16x2*)&lv1[(2 * yy + 1) * 48 + 2 * xx];
      lv2[c2] = (f16)(((float)a[0] + (float)a[1]) + ((float)bb[0] + (float)bb[1]));
    }
    __threadfence_block();
    // --- lvl3 ---
    if (lane < 60) {
      int yy = lane / 12, xx = lane - yy * 12;
      f16x2 a = *(const f16x2*)&lv2[(2 * yy) * 24 + 2 * xx];
      f16x2 bb = *(const f16x2*)&lv2[(2 * yy + 1) * 24 + 2 * xx];
      lv3[lane] = (f16)(((float)a[0] + (float)a[1]) + ((float)bb[0] + (float)bb[1]));
    }
    __threadfence_block();
    // --- 324 outputs ---
    for (int c = lane; c < 324; c += 64) {
      int lvl = c / 81, rem = c - lvl * 81;
      int k0 = rem / 9, k1 = rem - k0 * 9;
      const float wdiv[4] = {1.f, 0.25f, 0.0625f, 0.015625f};
      const int Wi[4] = {96, 48, 24, 12}, Hi[4] = {46, 23, 11, 5};
      // reference quirk: x pairs with d[k0], y with d[k1]
      float xq = clx / (float)(1 << lvl) + (float)(k0 - 4);
      float yq = cly / (float)(1 << lvl) + (float)(k1 - 4);
      float x0f = floorf(xq), y0f = floorf(yq);
      int x0 = (int)x0f, y0 = (int)y0f;
      float wx1 = xq - x0f, wx0f_ = 1.f - wx1;
      float wy1 = yq - y0f, wy0f_ = 1.f - wy1;
      int Wl = Wi[lvl], Hl = Hi[lvl];
      float v = 0.f;
#pragma unroll
      for (int dy = 0; dy < 2; ++dy)
#pragma unroll
        for (int dx = 0; dx < 2; ++dx) {
          int xi = x0 + dx, yi = y0 + dy;
          if (xi >= 0 && xi < Wl && yi >= 0 && yi < Hl) {
            float pv;
            if (lvl == 0)
              pv = __builtin_amdgcn_exp2f(
                  ((float)winW[wave][yi - wy0][xi - xb] - m) * L2E);
            else if (lvl == 1) pv = (float)lv1[yi * 48 + xi];
            else if (lvl == 2) pv = (float)lv2[yi * 24 + xi];
            else               pv = (float)lv3[yi * 12 + xi];
            v += pv * (dx ? wx1 : wx0f_) * (dy ? wy1 : wy0f_);
          }
        }
      int hh = hw / NW, wcol = hw - hh * NW;
      int chn = lvl * 81 + k0 * 9 + k1;
      out[((size_t)(b * 324 + chn) * NH + hh) * NW + wcol] = v * wdiv[lvl] * rinv;
    }
    __threadfence_block();
  }
}

// ============ Fallback: R4 fused kernel (verbatim, proven) ============
__global__ __launch_bounds__(1024) void attn_lookup(
    const float* __restrict__ coords1, const float* __restrict__ clup,
    const char* __restrict__ ws, float* __restrict__ out) {
  __shared__ f16 S[16 * SSTR];
  __shared__ f16 lv1[4][1104];
  __shared__ f16 lv2[4][264];
  __shared__ f16 lv3[4][60];
  __shared__ float wmax[16][16];
  __shared__ float wpart[16];
  __shared__ float u0s[16], u1s[16], clxs[16], clys[16], rinv[16], rowmaxS[16];
  const int tid = threadIdx.x;
  const int blk0 = blockIdx.x;
  const int xcd = blk0 & 7;
  const int b = xcd >> 2;
  const int hw0 = ((blk0 >> 3) * 4 + (xcd & 3)) * 16;
  const float* GS = (const float*)(ws + OFF_GS);
  if (tid < 16) {
    int hw = hw0 + tid;
    float cy = coords1[(b * 2 + 1) * NHW + hw];
    float cx = coords1[(b * 2 + 0) * NHW + hw];
    u0s[tid] = cy * GS[0] + cx * GS[2];
    u1s[tid] = cy * GS[1] + cx * GS[3];
    clxs[tid] = clup[(b * 2 + 0) * NHW + hw];
    clys[tid] = clup[(b * 2 + 1) * NHW + hw];
  }
  const f16* qb = (const f16*)(ws + OFF_Q);
  const f16* kb = (const f16*)(ws + OFF_K);
  const int lane = tid & 63;
  const int arow = lane & 15, akq = (lane >> 4) * 8;
  const int i0 = (lane >> 4) * 4;
  f16x8 afrag[8];
#pragma unroll
  for (int ks = 0; ks < 8; ++ks)
    afrag[ks] = *(const f16x8*)&qb[(size_t)(b * NHW + hw0 + arow) * ND + ks * 32 + akq];
  __syncthreads();
  float u0r[4], u1r[4];
#pragma unroll
  for (int r = 0; r < 4; ++r) { u0r[r] = u0s[i0 + r]; u1r[r] = u1s[i0 + r]; }
  const int wave = tid >> 6;
  float pmax[4] = {-3e38f, -3e38f, -3e38f, -3e38f};
  {
    const int cnt = (NTILES - wave + 15) / 16;
    const f16* kp = &kb[(size_t)(b * NHW + wave * 16 + arow) * ND + akq];
    const size_t tstep = (size_t)256 * ND;
    int nt = wave;
    f16x8 h0[4], h1[4];
#pragma unroll
    for (int s = 0; s < 4; ++s) h0[s] = *(const f16x8*)&kp[s * 32];
    for (int i = 0; i < cnt; ++i) {
      f32x4 acc0 = {}, acc1 = {};
#pragma unroll
      for (int s = 0; s < 4; ++s) h1[s] = *(const f16x8*)&kp[128 + s * 32];
      acc0 = __builtin_amdgcn_mfma_f32_16x16x32_f16(afrag[0], h0[0], acc0, 0, 0, 0);
      acc1 = __builtin_amdgcn_mfma_f32_16x16x32_f16(afrag[1], h0[1], acc1, 0, 0, 0);
      acc0 = __builtin_amdgcn_mfma_f32_16x16x32_f16(afrag[2], h0[2], acc0, 0, 0, 0);
      acc1 = __builtin_amdgcn_mfma_f32_16x16x32_f16(afrag[3], h0[3], acc1, 0, 0, 0);
      const f16* kpn = kp + tstep;
      if (i + 1 < cnt) {
#pragma unroll
        for (int s = 0; s < 4; ++s) h0[s] = *(const f16x8*)&kpn[s * 32];
      }
      acc0 = __builtin_amdgcn_mfma_f32_16x16x32_f16(afrag[4], h1[0], acc0, 0, 0, 0);
      acc1 = __builtin_amdgcn_mfma_f32_16x16x32_f16(afrag[5], h1[1], acc1, 0, 0, 0);
      acc0 = __builtin_amdgcn_mfma_f32_16x16x32_f16(afrag[6], h1[2], acc0, 0, 0, 0);
      acc1 = __builtin_amdgcn_mfma_f32_16x16x32_f16(afrag[7], h1[3], acc1, 0, 0, 0);
      int j = nt * 16 + (lane & 15);
      int yj = j / NW;
      float yf = (float)yj, xf = (float)(j - yj * NW);
#pragma unroll
      for (int r = 0; r < 4; ++r) {
        float s = acc0[r] + acc1[r] + u0r[r] * yf + u1r[r] * xf;
        pmax[r] = fmaxf(pmax[r], s);
        S[(i0 + r) * SSTR + j] = (f16)s;
      }
      kp = kpn; nt += 16;
    }
  }
#pragma unroll
  for (int off = 1; off < 16; off <<= 1)
#pragma unroll
    for (int r = 0; r < 4; ++r) pmax[r] = fmaxf(pmax[r], __shfl_xor(pmax[r], off));
  if ((lane & 15) == 0) {
#pragma unroll
    for (int r = 0; r < 4; ++r) wmax[wave][i0 + r] = pmax[r];
  }
  __syncthreads();
  if (tid < 16) {
    float m = wmax[0][tid];
#pragma unroll
    for (int w = 1; w < 16; ++w) m = fmaxf(m, wmax[w][tid]);
    rowmaxS[tid] = m;
  }
  __syncthreads();
  const int rgrp = tid >> 8, ts = tid & 255;
  for (int p = 0; p < 4; ++p) {
    const int r = p * 4 + rgrp;
    const f16* Sr = &S[r * SSTR];
    const float m = rowmaxS[r];
    float psum = 0.f;
    for (int c = ts; c < 1104; c += 256) {
      int yy = c / 48, xx = c - yy * 48;
      f16x2 a = *(const f16x2*)&Sr[(2 * yy) * NW + 2 * xx];
      f16x2 bb = *(const f16x2*)&Sr[(2 * yy + 1) * NW + 2 * xx];
      float e0 = __builtin_amdgcn_exp2f(((float)a[0] - m) * L2E);
      float e1 = __builtin_amdgcn_exp2f(((float)a[1] - m) * L2E);
      float e2 = __builtin_amdgcn_exp2f(((float)bb[0] - m) * L2E);
      float e3 = __builtin_amdgcn_exp2f(((float)bb[1] - m) * L2E);
      float s4 = (e0 + e1) + (e2 + e3);
      lv1[rgrp][c] = (f16)s4;
      psum += s4;
    }
#pragma unroll
    for (int off = 1; off < 64; off <<= 1) psum += __shfl_xor(psum, off);
    if (lane == 0) wpart[tid >> 6] = psum;
    __syncthreads();
    if (tid < 4)
      rinv[p * 4 + tid] = 1.f / (((wpart[tid * 4] + wpart[tid * 4 + 1]) +
                                  (wpart[tid * 4 + 2] + wpart[tid * 4 + 3])));
    for (int c2 = ts; c2 < 264; c2 += 256) {
      int yy = c2 / 24, xx = c2 - yy * 24;
      f16x2 a = *(const f16x2*)&lv1[rgrp][(2 * yy) * 48 + 2 * xx];
      f16x2 bb = *(const f16x2*)&lv1[rgrp][(2 * yy + 1) * 48 + 2 * xx];
      lv2[rgrp][c2] = (f16)(((float)a[0] + (float)a[1]) + ((float)bb[0] + (float)bb[1]));
    }
    __syncthreads();
    if (ts < 60) {
      int yy = ts / 12, xx = ts - yy * 12;
      f16x2 a = *(const f16x2*)&lv2[rgrp][(2 * yy) * 24 + 2 * xx];
      f16x2 bb = *(const f16x2*)&lv2[rgrp][(2 * yy + 1) * 24 + 2 * xx];
      lv3[rgrp][ts] = (f16)(((float)a[0] + (float)a[1]) + ((float)bb[0] + (float)bb[1]));
    }
    __syncthreads();
    for (int idx = tid; idx < 1296; idx += 1024) {
      int rl = idx / 324, c = idx - rl * 324;
      int rr = p * 4 + rl;
      int lvl = c / 81, rem = c - lvl * 81;
      int k0 = rem / 9, k1 = rem - k0 * 9;
      const float wdiv[4] = {1.f, 0.25f, 0.0625f, 0.015625f};
      const int Wi[4] = {96, 48, 24, 12}, Hi[4] = {46, 23, 11, 5};
      float m2 = rowmaxS[rr];
      float xq = clxs[rr] / (float)(1 << lvl) + (float)(k0 - 4);
      float yq = clys[rr] / (float)(1 << lvl) + (float)(k1 - 4);
      float x0f = floorf(xq), y0f = floorf(yq);
      int x0 = (int)x0f, y0 = (int)y0f;
      float wx1 = xq - x0f, wx0 = 1.f - wx1;
      float wy1 = yq - y0f, wy0 = 1.f - wy1;
      int Wl = Wi[lvl], Hl = Hi[lvl];
      float v = 0.f;
#pragma unroll
      for (int dy = 0; dy < 2; ++dy)
#pragma unroll
        for (int dx = 0; dx < 2; ++dx) {
          int xi = x0 + dx, yi = y0 + dy;
          if (xi >= 0 && xi < Wl && yi >= 0 && yi < Hl) {
            float pv;
            if (lvl == 0)
              pv = __builtin_amdgcn_exp2f(((float)S[rr * SSTR + yi * NW + xi] - m2) * L2E);
            else if (lvl == 1) pv = (float)lv1[rl][yi * 48 + xi];
            else if (lvl == 2) pv = (float)lv2[rl][yi * 24 + xi];
            else               pv = (float)lv3[rl][yi * 12 + xi];
            v += pv * (dx ? wx1 : wx0) * (dy ? wy1 : wy0);
          }
        }
      int hw = hw0 + rr;
      int h = hw / NW, w = hw - h * NW;
      int chn = lvl * 81 + k0 * 9 + k1;
      out[((size_t)(b * 324 + chn) * NH + h) * NW + w] = v * wdiv[lvl] * rinv[rr];
    }
    __syncthreads();
  }
}

extern "C" void kernel_launch(void* const* d_in, const int* in_sizes, int n_in,
                              void* d_out, int out_size, void* d_ws, size_t ws_size,
                              hipStream_t stream) {
  const float* fmap1 = (const float*)d_in[0];
  const float* fmap2 = (const float*)d_in[1];
  const float* coords1 = (const float*)d_in[2];
  const float* clup = (const float*)d_in[3];
  const float* Wf = (const float*)d_in[4];
  const float* bf = (const float*)d_in[5];
  const float* Wpos = (const float*)d_in[6];
  const float* Wq = (const float*)d_in[7];
  const float* Wk = (const float*)d_in[8];
  char* ws = (char*)d_ws;
  float* out = (float*)d_out;

  prep_kernel<<<dim3(258), dim3(256), 0, stream>>>(Wf, bf, Wpos, Wq, Wk, ws);
  qk_gemm<<<dim3(138, 1, 2), dim3(256), 0, stream>>>(fmap1, fmap2, coords1, ws);
  if (ws_size >= (size_t)WS_NEED) {
    score_gemm<<<dim3(46 * 16), dim3(384), 0, stream>>>(coords1, ws);
    lookup_kernel<<<dim3(NB * NTILES), dim3(512), 0, stream>>>(clup, ws, out);
  } else {
    attn_lookup<<<dim3(NB * NTILES), dim3(1024), 0, stream>>>(coords1, clup, ws, out);
  }
}

// Round 19
// 131.660 us; speedup vs baseline: 1.1160x; 1.1160x over previous
//
#include <hip/hip_runtime.h>
#include <cstdint>

typedef _Float16 f16;
typedef __attribute__((ext_vector_type(2))) _Float16 f16x2;
typedef __attribute__((ext_vector_type(4))) _Float16 f16x4;
typedef __attribute__((ext_vector_type(8))) _Float16 f16x8;
typedef __attribute__((ext_vector_type(4))) float f32x4;

#define NB 2
#define NH 46
#define NW 96
#define NHW 4416
#define ND 256
#define NTILES 276   // NHW / 16
#define SSTR 4424    // fused-path LDS S stride
#define L2E 1.44269504f

// ---- workspace byte offsets ----
#define OFF_WFQ 0          // (Wf@Wq)/16  f16 [256][256]
#define OFF_WFK 131072     // Wf@Wk       f16 [256][256]
#define OFF_PQ  262144     // (Wpos@Wq)/16 f32 [2][256]
#define OFF_PK  264192     // Wpos@Wk      f32 [2][256]
#define OFF_BQ  266240     // (bf@Wq)/16   f32 [256]
#define OFF_BK  267264     // bf@Wk        f32 [256]
#define OFF_GS  268288     // (Wpos@Wposᵀ)/16 f32 [2][2]
#define OFF_Q   268544     // q/16 f16 [8832][256]
#define OFF_K   4790528    // k    f16 [8832][256]
// ---- unfused-path extras ----
#define OFF_RM  9312512    // partial row max f32 [2][4][4416]
#define OFF_S   9453824    // scores f16 [2][4416][SCOL]
#define SCOL    4432       // 4416 + 16 pad
#define WS_NEED 87740672UL // OFF_S + 2*4416*4432*2

// ============ K0: tiny weight-product precompute ============
__global__ __launch_bounds__(256) void prep_kernel(
    const float* __restrict__ Wf, const float* __restrict__ bf,
    const float* __restrict__ Wpos, const float* __restrict__ Wq,
    const float* __restrict__ Wk, char* __restrict__ ws) {
  f16* WFQ = (f16*)(ws + OFF_WFQ);
  f16* WFK = (f16*)(ws + OFF_WFK);
  float* PQ = (float*)(ws + OFF_PQ);
  float* PK = (float*)(ws + OFF_PK);
  float* BQ = (float*)(ws + OFF_BQ);
  float* BK = (float*)(ws + OFF_BK);
  float* GS = (float*)(ws + OFF_GS);
  int bid = blockIdx.x, d = threadIdx.x;
  if (bid < 256) {
    int c = bid;
    float aq = 0.f, ak = 0.f;
#pragma unroll 8
    for (int t = 0; t < 256; ++t) {
      float wf = Wf[c * 256 + t];
      aq += wf * Wq[t * 256 + d];
      ak += wf * Wk[t * 256 + d];
    }
    WFQ[c * 256 + d] = (f16)(aq * 0.0625f);
    WFK[c * 256 + d] = (f16)ak;
  } else if (bid == 256) {
    float pq0 = 0, pq1 = 0, pk0 = 0, pk1 = 0, bq = 0, bk = 0;
#pragma unroll 4
    for (int c = 0; c < 256; ++c) {
      float wq = Wq[c * 256 + d], wk = Wk[c * 256 + d];
      pq0 += Wpos[c] * wq;       pq1 += Wpos[256 + c] * wq;
      pk0 += Wpos[c] * wk;       pk1 += Wpos[256 + c] * wk;
      bq  += bf[c] * wq;         bk  += bf[c] * wk;
    }
    PQ[d] = pq0 * 0.0625f; PQ[256 + d] = pq1 * 0.0625f;
    PK[d] = pk0;           PK[256 + d] = pk1;
    BQ[d] = bq * 0.0625f;  BK[d] = bk;
  } else if (d < 4) {
    int a = d >> 1, b2 = d & 1;
    float g = 0;
    for (int t = 0; t < 256; ++t) g += Wpos[a * 256 + t] * Wpos[b2 * 256 + t];
    GS[d] = g * 0.0625f;
  }
}

// ============ K1: q_s/k = fmapᵀ @ Wfx + rank-2 pos + bias (256-col tile) ============
// grid (138, 1, 2): x = 64-row tile, z = 0:q 1:k. 256 thr (4 waves). [R15 proven]
__global__ __launch_bounds__(256, 2) void qk_gemm(
    const float* __restrict__ fmap1, const float* __restrict__ fmap2,
    const float* __restrict__ coords1, char* __restrict__ ws) {
  __shared__ f16 As[64 * 40];
  __shared__ f16 Bs[256 * 40];
  __shared__ float py[64], px[64];
  const int z = blockIdx.z;
  const float* fmap = z ? fmap2 : fmap1;
  const f16* Wt = (const f16*)(ws + (z ? OFF_WFK : OFF_WFQ));
  const float* P = (const float*)(ws + (z ? OFF_PK : OFF_PQ));
  const float* bias = (const float*)(ws + (z ? OFF_BK : OFF_BQ));
  f16* outb = (f16*)(ws + (z ? OFF_K : OFF_Q));
  const int t = threadIdx.x;
  const int g0 = blockIdx.x * 64;
  const int b = g0 / NHW;
  const int hwb = g0 - b * NHW;
  if (t < 64) {
    int hw = hwb + t;
    if (z == 0) {
      py[t] = coords1[(b * 2 + 1) * NHW + hw];
      px[t] = coords1[(b * 2 + 0) * NHW + hw];
    } else {
      int y = hw / NW;
      py[t] = (float)y;
      px[t] = (float)(hw - y * NW);
    }
  }
  const int lane = t & 63, wave = t >> 6;
  const int wr = (wave >> 1) * 32, wc0 = (wave & 1) * 128;
  const int hwl = t & 63, cl0 = t >> 6;
  const int dd = t & 127, ch = t >> 7;
  f32x4 acc[2][8] = {};
  for (int kt = 0; kt < 8; ++kt) {
    int kk = kt * 32;
    __syncthreads();
#pragma unroll
    for (int i = 0; i < 8; ++i) {
      int c = cl0 + i * 4;
      As[hwl * 40 + c] = (f16)fmap[(size_t)(b * ND + kk + c) * NHW + hwb + hwl];
    }
#pragma unroll
    for (int i = 0; i < 16; ++i) {
      int c = ch * 16 + i;
      Bs[dd * 40 + c] = Wt[(kk + c) * ND + dd];
      Bs[(dd + 128) * 40 + c] = Wt[(kk + c) * ND + dd + 128];
    }
    __syncthreads();
    int row = lane & 15, kq = (lane >> 4) * 8;
    f16x8 a0 = *(const f16x8*)&As[(wr + row) * 40 + kq];
    f16x8 a1 = *(const f16x8*)&As[(wr + 16 + row) * 40 + kq];
#pragma unroll
    for (int s = 0; s < 8; ++s) {
      f16x8 bs = *(const f16x8*)&Bs[(wc0 + 16 * s + row) * 40 + kq];
      acc[0][s] = __builtin_amdgcn_mfma_f32_16x16x32_f16(a0, bs, acc[0][s], 0, 0, 0);
      acc[1][s] = __builtin_amdgcn_mfma_f32_16x16x32_f16(a1, bs, acc[1][s], 0, 0, 0);
    }
  }
#pragma unroll
  for (int fi = 0; fi < 2; ++fi)
#pragma unroll
    for (int s = 0; s < 8; ++s)
#pragma unroll
      for (int r = 0; r < 4; ++r) {
        int rowl = wr + fi * 16 + (lane >> 4) * 4 + r;
        int d = wc0 + s * 16 + (lane & 15);
        float v = acc[fi][s][r] + bias[d] + py[rowl] * P[d] + px[rowl] * P[ND + d];
        outb[(size_t)(g0 + rowl) * ND + d] = (f16)v;
      }
}

// ============ Ka: scores GEMM v6 (R10 TRUE verbatim — proven 58.7 µs) ============
__global__ __launch_bounds__(384, 2) void score_gemm(
    const float* __restrict__ coords1, char* __restrict__ ws) {
  __shared__ f16 kls[2][32][264];      // K-tile dbuf, row-pad 264
  __shared__ f16 stw[6][16][36];       // per-wave repack [qrow][32col + pad]
  __shared__ float u0s[96], u1s[96];
  const int tid = threadIdx.x;
  const int blk = blockIdx.x;
  const int xcd = blk & 7;
  const int b = xcd >> 2, nq = xcd & 3;
  const int hw0 = (blk >> 3) * 96;
  const int j00 = nq * 1104;
  const float* GS = (const float*)(ws + OFF_GS);
  if (tid < 96) {
    int hw = hw0 + tid;
    float cy = coords1[(b * 2 + 1) * NHW + hw];
    float cx = coords1[(b * 2 + 0) * NHW + hw];
    u0s[tid] = cy * GS[0] + cx * GS[2];
    u1s[tid] = cy * GS[1] + cx * GS[3];
  }
  const f16* __restrict__ qb = (const f16*)(ws + OFF_Q);
  const f16* __restrict__ kb = (const f16*)(ws + OFF_K);
  f16* __restrict__ gSb = (f16*)(ws + OFF_S) + ((size_t)b * NHW + hw0) * SCOL;
  float* __restrict__ rmG = (float*)(ws + OFF_RM);
  const int lane = tid & 63, wave = tid >> 6;   // 6 waves
  const int q = lane & 15, h = lane >> 4;
  // wave's 16 Q-rows, full K=256: 32 VGPR
  f16x8 qfrag[8];
#pragma unroll
  for (int ks = 0; ks < 8; ++ks)
    qfrag[ks] = *(const f16x8*)&qb[(size_t)(b * NHW + hw0 + wave * 16 + q) * ND + ks * 32 + h * 8];
  // stage iter-0 tile into kls[0]
  for (int c = tid; c < 32 * 32; c += 384) {
    int r = c >> 5, cc = c & 31;
    *(f16x8*)&kls[0][r][cc * 8] =
        *(const f16x8*)&kb[(size_t)(b * NHW + j00 + r) * ND + cc * 8];
  }
  __syncthreads();
  const float u0m = u0s[wave * 16 + q], u1m = u1s[wave * 16 + q];
  float pmax = -3e38f;
  const int srow = lane >> 2, scg = lane & 3;   // store-phase mapping

  for (int it = 0; it <= 34; ++it) {            // 34 x 32-col + 1 x 16-col
    const int buf = it & 1;
    const int jp = j00 + it * 32;
    const bool full = (it < 34);
    // stage next tile into buf^1 (no one reads buf^1 this iter)
    if (it < 34) {
      const int nW = (it < 33) ? 32 : 16;
      const int jn = j00 + (it + 1) * 32;
      for (int c = tid; c < nW * 32; c += 384) {
        int r = c >> 5, cc = c & 31;
        *(f16x8*)&kls[buf ^ 1][r][cc * 8] =
            *(const f16x8*)&kb[(size_t)(b * NHW + jn + r) * ND + cc * 8];
      }
    }
    // compute from kls[buf]
    f32x4 acc0 = {}, acc1 = {};
#pragma unroll
    for (int ks = 0; ks < 8; ++ks) {
      f16x8 kf = *(const f16x8*)&kls[buf][q][ks * 32 + h * 8];
      acc0 = __builtin_amdgcn_mfma_f32_16x16x32_f16(kf, qfrag[ks], acc0, 0, 0, 0);
    }
    if (full) {
#pragma unroll
      for (int ks = 0; ks < 8; ++ks) {
        f16x8 kf = *(const f16x8*)&kls[buf][16 + q][ks * 32 + h * 8];
        acc1 = __builtin_amdgcn_mfma_f32_16x16x32_f16(kf, qfrag[ks], acc1, 0, 0, 0);
      }
    }
    // epilogue: bias + running max + pack to stw
    {
      f16x4 v0, v1;
#pragma unroll
      for (int r = 0; r < 4; ++r) {
        int j = jp + h * 4 + r;
        int yj = j / NW;
        float s = acc0[r] + u0m * (float)yj + u1m * (float)(j - yj * NW);
        pmax = fmaxf(pmax, s);
        v0[r] = (f16)s;
      }
      *(f16x4*)&stw[wave][q][h * 4] = v0;
      if (full) {
#pragma unroll
        for (int r = 0; r < 4; ++r) {
          int j = jp + 16 + h * 4 + r;
          int yj = j / NW;
          float s = acc1[r] + u0m * (float)yj + u1m * (float)(j - yj * NW);
          pmax = fmaxf(pmax, s);
          v1[r] = (f16)s;
        }
        *(f16x4*)&stw[wave][q][16 + h * 4] = v1;
      }
    }
    // store: 64B (or 32B tail) contiguous per row
    if (full) {
      f16x8 row8 = *(const f16x8*)&stw[wave][srow][scg * 8];
      *(f16x8*)&gSb[(size_t)(wave * 16 + srow) * SCOL + jp + scg * 8] = row8;
    } else {
      f16x4 row4 = *(const f16x4*)&stw[wave][srow][scg * 4];
      *(f16x4*)&gSb[(size_t)(wave * 16 + srow) * SCOL + jp + scg * 4] = row4;
    }
    __syncthreads();   // stage(it+1) done AND compute(buf) done before reuse
  }
  // rowmax: lane's pmax covers its q-row over all its h-cols; reduce h-groups
  pmax = fmaxf(pmax, __shfl_xor(pmax, 16));
  pmax = fmaxf(pmax, __shfl_xor(pmax, 32));
  if (lane < 16)
    rmG[((size_t)b * 4 + nq) * NHW + hw0 + wave * 16 + q] = pmax;
}

// ============ Kb: lookup v2 — one wave per row, barrier-free, windowed lvl0 ============
// [R14 proven] 552 blocks x 512 thr (8 waves x 2 rows each). Reads rmG.
__global__ __launch_bounds__(512) void lookup_kernel(
    const float* __restrict__ clup, const char* __restrict__ ws,
    float* __restrict__ out) {
  __shared__ f16 lv1W[8][1104];
  __shared__ f16 lv2W[8][264];
  __shared__ f16 lv3W[8][60];
  __shared__ f16 winW[8][10][24];
  const int tid = threadIdx.x;
  const int blk0 = blockIdx.x;
  const int xcd = blk0 & 7;
  const int b = xcd >> 2;
  const int hw0 = ((blk0 >> 3) * 4 + (xcd & 3)) * 16;
  const f16* gS = (const f16*)(ws + OFF_S);
  const float* rmG = (const float*)(ws + OFF_RM);
  const int lane = tid & 63, wave = tid >> 6;
  f16* lv1 = lv1W[wave];
  f16* lv2 = lv2W[wave];
  f16* lv3 = lv3W[wave];

  for (int rr2 = 0; rr2 < 2; ++rr2) {
    const int r = wave * 2 + rr2;
    const int hw = hw0 + r;
    const size_t grow = (size_t)b * NHW + hw;
    const f16* sp = gS + grow * SCOL;
    const float clx = clup[(b * 2 + 0) * NHW + hw];
    const float cly = clup[(b * 2 + 1) * NHW + hw];
    const float* rp = rmG + (size_t)b * 4 * NHW + hw;
    const float m = fmaxf(fmaxf(rp[0], rp[NHW]), fmaxf(rp[2 * NHW], rp[3 * NHW]));
    const int wy0 = (int)floorf(cly) - 4;
    const int wx0 = (int)floorf(clx) - 4;
    const int xb = (wx0 >> 3) << 3;       // 8-aligned floor (works for negatives)
    // --- stage 10x24 raw-S window (lanes 0..29: row=l/3, chunk=l%3) ---
    if (lane < 30) {
      int r10 = lane / 3, chk = lane - r10 * 3;
      int yy = wy0 + r10;
      int xc = xb + chk * 8;
      if (yy >= 0 && yy < NH) {
        if (xc >= 0 && xc + 8 <= NW) {
          *(f16x8*)&winW[wave][r10][chk * 8] = *(const f16x8*)&sp[yy * NW + xc];
        } else {
#pragma unroll
          for (int e = 0; e < 8; ++e) {
            int x = xc + e;
            winW[wave][r10][chk * 8 + e] =
                (x >= 0 && x < NW) ? sp[yy * NW + x] : (f16)0.f;
          }
        }
      }
    }
    // --- lvl1: exp-pool 2x2, 4 cells per f16x8-pair (u = y1*12 + g) ---
    float psum = 0.f;
    for (int u = lane; u < 276; u += 64) {
      int y1 = u / 12, g = u - y1 * 12;
      f16x8 A = *(const f16x8*)&sp[(2 * y1) * NW + g * 8];
      f16x8 B = *(const f16x8*)&sp[(2 * y1 + 1) * NW + g * 8];
      f16x4 v;
#pragma unroll
      for (int e = 0; e < 4; ++e) {
        float e00 = __builtin_amdgcn_exp2f(((float)A[2 * e] - m) * L2E);
        float e01 = __builtin_amdgcn_exp2f(((float)A[2 * e + 1] - m) * L2E);
        float e10 = __builtin_amdgcn_exp2f(((float)B[2 * e] - m) * L2E);
        float e11 = __builtin_amdgcn_exp2f(((float)B[2 * e + 1] - m) * L2E);
        float s4 = (e00 + e01) + (e10 + e11);
        v[e] = (f16)s4;
        psum += s4;
      }
      *(f16x4*)&lv1[y1 * 48 + g * 4] = v;
    }
#pragma unroll
    for (int off = 1; off < 64; off <<= 1) psum += __shfl_xor(psum, off);
    const float rinv = 1.f / psum;
    __threadfence_block();
    // --- lvl2 ---
    for (int c2 = lane; c2 < 264; c2 += 64) {
      int yy = c2 / 24, xx = c2 - yy * 24;
      f16x2 a = *(const f16x2*)&lv1[(2 * yy) * 48 + 2 * xx];
      f16x2 bb = *(const f16x2*)&lv1[(2 * yy + 1) * 48 + 2 * xx];
      lv2[c2] = (f16)(((float)a[0] + (float)a[1]) + ((float)bb[0] + (float)bb[1]));
    }
    __threadfence_block();
    // --- lvl3 ---
    if (lane < 60) {
      int yy = lane / 12, xx = lane - yy * 12;
      f16x2 a = *(const f16x2*)&lv2[(2 * yy) * 24 + 2 * xx];
      f16x2 bb = *(const f16x2*)&lv2[(2 * yy + 1) * 24 + 2 * xx];
      lv3[lane] = (f16)(((float)a[0] + (float)a[1]) + ((float)bb[0] + (float)bb[1]));
    }
    __threadfence_block();
    // --- 324 outputs ---
    for (int c = lane; c < 324; c += 64) {
      int lvl = c / 81, rem = c - lvl * 81;
      int k0 = rem / 9, k1 = rem - k0 * 9;
      const float wdiv[4] = {1.f, 0.25f, 0.0625f, 0.015625f};
      const int Wi[4] = {96, 48, 24, 12}, Hi[4] = {46, 23, 11, 5};
      // reference quirk: x pairs with d[k0], y with d[k1]
      float xq = clx / (float)(1 << lvl) + (float)(k0 - 4);
      float yq = cly / (float)(1 << lvl) + (float)(k1 - 4);
      float x0f = floorf(xq), y0f = floorf(yq);
      int x0 = (int)x0f, y0 = (int)y0f;
      float wx1 = xq - x0f, wx0f_ = 1.f - wx1;
      float wy1 = yq - y0f, wy0f_ = 1.f - wy1;
      int Wl = Wi[lvl], Hl = Hi[lvl];
      float v = 0.f;
#pragma unroll
      for (int dy = 0; dy < 2; ++dy)
#pragma unroll
        for (int dx = 0; dx < 2; ++dx) {
          int xi = x0 + dx, yi = y0 + dy;
          if (xi >= 0 && xi < Wl && yi >= 0 && yi < Hl) {
            float pv;
            if (lvl == 0)
              pv = __builtin_amdgcn_exp2f(
                  ((float)winW[wave][yi - wy0][xi - xb] - m) * L2E);
            else if (lvl == 1) pv = (float)lv1[yi * 48 + xi];
            else if (lvl == 2) pv = (float)lv2[yi * 24 + xi];
            else               pv = (float)lv3[yi * 12 + xi];
            v += pv * (dx ? wx1 : wx0f_) * (dy ? wy1 : wy0f_);
          }
        }
      int hh = hw / NW, wcol = hw - hh * NW;
      int chn = lvl * 81 + k0 * 9 + k1;
      out[((size_t)(b * 324 + chn) * NH + hh) * NW + wcol] = v * wdiv[lvl] * rinv;
    }
    __threadfence_block();
  }
}

// ============ Fallback: R4 fused kernel (verbatim, proven) ============
__global__ __launch_bounds__(1024) void attn_lookup(
    const float* __restrict__ coords1, const float* __restrict__ clup,
    const char* __restrict__ ws, float* __restrict__ out) {
  __shared__ f16 S[16 * SSTR];
  __shared__ f16 lv1[4][1104];
  __shared__ f16 lv2[4][264];
  __shared__ f16 lv3[4][60];
  __shared__ float wmax[16][16];
  __shared__ float wpart[16];
  __shared__ float u0s[16], u1s[16], clxs[16], clys[16], rinv[16], rowmaxS[16];
  const int tid = threadIdx.x;
  const int blk0 = blockIdx.x;
  const int xcd = blk0 & 7;
  const int b = xcd >> 2;
  const int hw0 = ((blk0 >> 3) * 4 + (xcd & 3)) * 16;
  const float* GS = (const float*)(ws + OFF_GS);
  if (tid < 16) {
    int hw = hw0 + tid;
    float cy = coords1[(b * 2 + 1) * NHW + hw];
    float cx = coords1[(b * 2 + 0) * NHW + hw];
    u0s[tid] = cy * GS[0] + cx * GS[2];
    u1s[tid] = cy * GS[1] + cx * GS[3];
    clxs[tid] = clup[(b * 2 + 0) * NHW + hw];
    clys[tid] = clup[(b * 2 + 1) * NHW + hw];
  }
  const f16* qb = (const f16*)(ws + OFF_Q);
  const f16* kb = (const f16*)(ws + OFF_K);
  const int lane = tid & 63;
  const int arow = lane & 15, akq = (lane >> 4) * 8;
  const int i0 = (lane >> 4) * 4;
  f16x8 afrag[8];
#pragma unroll
  for (int ks = 0; ks < 8; ++ks)
    afrag[ks] = *(const f16x8*)&qb[(size_t)(b * NHW + hw0 + arow) * ND + ks * 32 + akq];
  __syncthreads();
  float u0r[4], u1r[4];
#pragma unroll
  for (int r = 0; r < 4; ++r) { u0r[r] = u0s[i0 + r]; u1r[r] = u1s[i0 + r]; }
  const int wave = tid >> 6;
  float pmax[4] = {-3e38f, -3e38f, -3e38f, -3e38f};
  {
    const int cnt = (NTILES - wave + 15) / 16;
    const f16* kp = &kb[(size_t)(b * NHW + wave * 16 + arow) * ND + akq];
    const size_t tstep = (size_t)256 * ND;
    int nt = wave;
    f16x8 h0[4], h1[4];
#pragma unroll
    for (int s = 0; s < 4; ++s) h0[s] = *(const f16x8*)&kp[s * 32];
    for (int i = 0; i < cnt; ++i) {
      f32x4 acc0 = {}, acc1 = {};
#pragma unroll
      for (int s = 0; s < 4; ++s) h1[s] = *(const f16x8*)&kp[128 + s * 32];
      acc0 = __builtin_amdgcn_mfma_f32_16x16x32_f16(afrag[0], h0[0], acc0, 0, 0, 0);
      acc1 = __builtin_amdgcn_mfma_f32_16x16x32_f16(afrag[1], h0[1], acc1, 0, 0, 0);
      acc0 = __builtin_amdgcn_mfma_f32_16x16x32_f16(afrag[2], h0[2], acc0, 0, 0, 0);
      acc1 = __builtin_amdgcn_mfma_f32_16x16x32_f16(afrag[3], h0[3], acc1, 0, 0, 0);
      const f16* kpn = kp + tstep;
      if (i + 1 < cnt) {
#pragma unroll
        for (int s = 0; s < 4; ++s) h0[s] = *(const f16x8*)&kpn[s * 32];
      }
      acc0 = __builtin_amdgcn_mfma_f32_16x16x32_f16(afrag[4], h1[0], acc0, 0, 0, 0);
      acc1 = __builtin_amdgcn_mfma_f32_16x16x32_f16(afrag[5], h1[1], acc1, 0, 0, 0);
      acc0 = __builtin_amdgcn_mfma_f32_16x16x32_f16(afrag[6], h1[2], acc0, 0, 0, 0);
      acc1 = __builtin_amdgcn_mfma_f32_16x16x32_f16(afrag[7], h1[3], acc1, 0, 0, 0);
      int j = nt * 16 + (lane & 15);
      int yj = j / NW;
      float yf = (float)yj, xf = (float)(j - yj * NW);
#pragma unroll
      for (int r = 0; r < 4; ++r) {
        float s = acc0[r] + acc1[r] + u0r[r] * yf + u1r[r] * xf;
        pmax[r] = fmaxf(pmax[r], s);
        S[(i0 + r) * SSTR + j] = (f16)s;
      }
      kp = kpn; nt += 16;
    }
  }
#pragma unroll
  for (int off = 1; off < 16; off <<= 1)
#pragma unroll
    for (int r = 0; r < 4; ++r) pmax[r] = fmaxf(pmax[r], __shfl_xor(pmax[r], off));
  if ((lane & 15) == 0) {
#pragma unroll
    for (int r = 0; r < 4; ++r) wmax[wave][i0 + r] = pmax[r];
  }
  __syncthreads();
  if (tid < 16) {
    float m = wmax[0][tid];
#pragma unroll
    for (int w = 1; w < 16; ++w) m = fmaxf(m, wmax[w][tid]);
    rowmaxS[tid] = m;
  }
  __syncthreads();
  const int rgrp = tid >> 8, ts = tid & 255;
  for (int p = 0; p < 4; ++p) {
    const int r = p * 4 + rgrp;
    const f16* Sr = &S[r * SSTR];
    const float m = rowmaxS[r];
    float psum = 0.f;
    for (int c = ts; c < 1104; c += 256) {
      int yy = c / 48, xx = c - yy * 48;
      f16x2 a = *(const f16x2*)&Sr[(2 * yy) * NW + 2 * xx];
      f16x2 bb = *(const f16x2*)&Sr[(2 * yy + 1) * NW + 2 * xx];
      float e0 = __builtin_amdgcn_exp2f(((float)a[0] - m) * L2E);
      float e1 = __builtin_amdgcn_exp2f(((float)a[1] - m) * L2E);
      float e2 = __builtin_amdgcn_exp2f(((float)bb[0] - m) * L2E);
      float e3 = __builtin_amdgcn_exp2f(((float)bb[1] - m) * L2E);
      float s4 = (e0 + e1) + (e2 + e3);
      lv1[rgrp][c] = (f16)s4;
      psum += s4;
    }
#pragma unroll
    for (int off = 1; off < 64; off <<= 1) psum += __shfl_xor(psum, off);
    if (lane == 0) wpart[tid >> 6] = psum;
    __syncthreads();
    if (tid < 4)
      rinv[p * 4 + tid] = 1.f / (((wpart[tid * 4] + wpart[tid * 4 + 1]) +
                                  (wpart[tid * 4 + 2] + wpart[tid * 4 + 3])));
    for (int c2 = ts; c2 < 264; c2 += 256) {
      int yy = c2 / 24, xx = c2 - yy * 24;
      f16x2 a = *(const f16x2*)&lv1[rgrp][(2 * yy) * 48 + 2 * xx];
      f16x2 bb = *(const f16x2*)&lv1[rgrp][(2 * yy + 1) * 48 + 2 * xx];
      lv2[rgrp][c2] = (f16)(((float)a[0] + (float)a[1]) + ((float)bb[0] + (float)bb[1]));
    }
    __syncthreads();
    if (ts < 60) {
      int yy = ts / 12, xx = ts - yy * 12;
      f16x2 a = *(const f16x2*)&lv2[rgrp][(2 * yy) * 24 + 2 * xx];
      f16x2 bb = *(const f16x2*)&lv2[rgrp][(2 * yy + 1) * 24 + 2 * xx];
      lv3[rgrp][ts] = (f16)(((float)a[0] + (float)a[1]) + ((float)bb[0] + (float)bb[1]));
    }
    __syncthreads();
    for (int idx = tid; idx < 1296; idx += 1024) {
      int rl = idx / 324, c = idx - rl * 324;
      int rr = p * 4 + rl;
      int lvl = c / 81, rem = c - lvl * 81;
      int k0 = rem / 9, k1 = rem - k0 * 9;
      const float wdiv[4] = {1.f, 0.25f, 0.0625f, 0.015625f};
      const int Wi[4] = {96, 48, 24, 12}, Hi[4] = {46, 23, 11, 5};
      float m2 = rowmaxS[rr];
      float xq = clxs[rr] / (float)(1 << lvl) + (float)(k0 - 4);
      float yq = clys[rr] / (float)(1 << lvl) + (float)(k1 - 4);
      float x0f = floorf(xq), y0f = floorf(yq);
      int x0 = (int)x0f, y0 = (int)y0f;
      float wx1 = xq - x0f, wx0 = 1.f - wx1;
      float wy1 = yq - y0f, wy0 = 1.f - wy1;
      int Wl = Wi[lvl], Hl = Hi[lvl];
      float v = 0.f;
#pragma unroll
      for (int dy = 0; dy < 2; ++dy)
#pragma unroll
        for (int dx = 0; dx < 2; ++dx) {
          int xi = x0 + dx, yi = y0 + dy;
          if (xi >= 0 && xi < Wl && yi >= 0 && yi < Hl) {
            float pv;
            if (lvl == 0)
              pv = __builtin_amdgcn_exp2f(((float)S[rr * SSTR + yi * NW + xi] - m2) * L2E);
            else if (lvl == 1) pv = (float)lv1[rl][yi * 48 + xi];
            else if (lvl == 2) pv = (float)lv2[rl][yi * 24 + xi];
            else               pv = (float)lv3[rl][yi * 12 + xi];
            v += pv * (dx ? wx1 : wx0) * (dy ? wy1 : wy0);
          }
        }
      int hw = hw0 + rr;
      int h = hw / NW, w = hw - h * NW;
      int chn = lvl * 81 + k0 * 9 + k1;
      out[((size_t)(b * 324 + chn) * NH + h) * NW + w] = v * wdiv[lvl] * rinv[rr];
    }
    __syncthreads();
  }
}

extern "C" void kernel_launch(void* const* d_in, const int* in_sizes, int n_in,
                              void* d_out, int out_size, void* d_ws, size_t ws_size,
                              hipStream_t stream) {
  const float* fmap1 = (const float*)d_in[0];
  const float* fmap2 = (const float*)d_in[1];
  const float* coords1 = (const float*)d_in[2];
  const float* clup = (const float*)d_in[3];
  const float* Wf = (const float*)d_in[4];
  const float* bf = (const float*)d_in[5];
  const float* Wpos = (const float*)d_in[6];
  const float* Wq = (const float*)d_in[7];
  const float* Wk = (const float*)d_in[8];
  char* ws = (char*)d_ws;
  float* out = (float*)d_out;

  prep_kernel<<<dim3(258), dim3(256), 0, stream>>>(Wf, bf, Wpos, Wq, Wk, ws);
  qk_gemm<<<dim3(138, 1, 2), dim3(256), 0, stream>>>(fmap1, fmap2, coords1, ws);
  if (ws_size >= (size_t)WS_NEED) {
    score_gemm<<<dim3(46 * 8), dim3(384), 0, stream>>>(coords1, ws);
    lookup_kernel<<<dim3(NB * NTILES), dim3(512), 0, stream>>>(clup, ws, out);
  } else {
    attn_lookup<<<dim3(NB * NTILES), dim3(1024), 0, stream>>>(coords1, clup, ws, out);
  }
}